// Round 10
// baseline (351.813 us; speedup 1.0000x reference)
//
#include <hip/hip_runtime.h>
#include <hip/hip_bf16.h>
#include <math.h>

#define ENC2 1024
#define DECD 1024
#define ATT 512
#define NBATCH 32
#define SEQ 2048
#define MTOT (NBATCH*SEQ)

#define BM 128
#define BN2 256
#define BK 32
#define LDK 40   // padded LDS row stride (80 B -> only 2-way bank alias, free)

typedef __attribute__((ext_vector_type(8))) short short8;
typedef __attribute__((ext_vector_type(4))) short short4v;
typedef __attribute__((ext_vector_type(4))) float f32x4;

static __device__ __forceinline__ unsigned pk2(float a, float b) {
  __hip_bfloat162 h = __float22bfloat162_rn(float2{a, b});  // v_cvt_pk_bf16_f32 (RNE)
  union { __hip_bfloat162 h; unsigned u; } c; c.h = h;
  return c.u;
}

static __device__ __forceinline__ float fast_tanh(float x) {
  float ax = fabsf(x);
  float e = __expf(2.f * ax);          // overflow -> inf -> t -> 1 (correct)
  float t = 1.f - 2.f / (e + 1.f);
  return copysignf(t, x);
}

// ---- fused prep (R7, unchanged): blocks 0..127 U_w -> U_wT bf16; 128..255 Wsb ----
__global__ __launch_bounds__(512) void prep_kernel(
    const float* __restrict__ U_w, short* __restrict__ U_wT,
    const float* __restrict__ dh, const float* __restrict__ W_w,
    const float* __restrict__ W_b, const float* __restrict__ U_b,
    float* __restrict__ Wsb) {
  __shared__ float tile[64][65];
  __shared__ float dsh[DECD];
  __shared__ float part[4][128];
  const int t = threadIdx.x;

  if (blockIdx.x < 128) {
    const int kt = blockIdx.x >> 3;
    const int ct = blockIdx.x & 7;
    const int k0 = kt * 64, c0 = ct * 64;
    const int r = t >> 3, cc = (t & 7) * 8;
    float4 v0 = *(const float4*)(U_w + (size_t)(k0 + r) * ATT + c0 + cc);
    float4 v1 = *(const float4*)(U_w + (size_t)(k0 + r) * ATT + c0 + cc + 4);
    tile[r][cc+0] = v0.x; tile[r][cc+1] = v0.y; tile[r][cc+2] = v0.z; tile[r][cc+3] = v0.w;
    tile[r][cc+4] = v1.x; tile[r][cc+5] = v1.y; tile[r][cc+6] = v1.z; tile[r][cc+7] = v1.w;
    __syncthreads();
    const int c = t >> 3, kk = (t & 7) * 8;
    union { short8 s; unsigned u[4]; } o;
    o.u[0] = pk2(tile[kk+0][c], tile[kk+1][c]);
    o.u[1] = pk2(tile[kk+2][c], tile[kk+3][c]);
    o.u[2] = pk2(tile[kk+4][c], tile[kk+5][c]);
    o.u[3] = pk2(tile[kk+6][c], tile[kk+7][c]);
    *(short8*)(U_wT + (size_t)(c0 + c) * ENC2 + k0 + kk) = o.s;
  } else {
    const int bid = blockIdx.x - 128;
    const int b  = bid >> 2;
    const int a0 = (bid & 3) * 128;
    for (int i = t; i < DECD; i += 512) dsh[i] = dh[(size_t)b * DECD + i];
    __syncthreads();
    const int ks = t >> 7;
    const int a  = t & 127;
    const float* wp = W_w + (size_t)(ks * 256) * ATT + a0 + a;
    float s0 = 0.f, s1 = 0.f, s2 = 0.f, s3 = 0.f;
    #pragma unroll 4
    for (int kk = 0; kk < 256; kk += 4) {
      s0 = fmaf(dsh[ks*256 + kk + 0], wp[(size_t)(kk + 0) * ATT], s0);
      s1 = fmaf(dsh[ks*256 + kk + 1], wp[(size_t)(kk + 1) * ATT], s1);
      s2 = fmaf(dsh[ks*256 + kk + 2], wp[(size_t)(kk + 2) * ATT], s2);
      s3 = fmaf(dsh[ks*256 + kk + 3], wp[(size_t)(kk + 3) * ATT], s3);
    }
    part[ks][a] = (s0 + s1) + (s2 + s3);
    __syncthreads();
    if (t < 128) {
      float v = part[0][t] + part[1][t] + part[2][t] + part[3][t];
      Wsb[(size_t)b * ATT + a0 + t] = v + W_b[a0 + t] + U_b[a0 + t];
    }
  }
}

// ---- main: GEMM (R2/R7 proven loop, untouched) + fused last-block softmax ----
__global__ __launch_bounds__(512) void energy_kernel(
    const float* __restrict__ A,      // encoder [MTOT][ENC2] f32
    const short* __restrict__ Bt,     // U_wT [ATT][ENC2] bf16
    const float* __restrict__ Wsb,    // [NBATCH][ATT]
    const float* __restrict__ vw,     // [ATT]
    float* __restrict__ epart,        // [2][MTOT]
    unsigned* __restrict__ cnt,       // [NBATCH] completion counters (zeroed)
    float* __restrict__ out)          // [NBATCH][SEQ] alpha
{
  __shared__ __align__(16) short As[2][BM * LDK];
  __shared__ __align__(16) short Bs[2][BN2 * LDK];
  __shared__ float eps[4][BM];
  __shared__ float redm[8], reds[8];
  __shared__ unsigned sflag;

  const int tid = threadIdx.x;
  const int bid = blockIdx.x;
  // XCD-pairing swizzle: bids 16g+j and 16g+j+8 share mt (same A rows), same XCD.
  const int mt = (bid >> 4) * 8 + (bid & 7);   // 0..511
  const int nt = (bid >> 3) & 1;               // pair member
  const int row0 = mt * BM;
  const int col0 = nt * BN2;
  const int bidx = row0 / SEQ;

  const int lane = tid & 63;
  const int wid  = tid >> 6;
  const int wm   = wid >> 2;    // 0..1
  const int wn   = wid & 3;     // 0..3

  const int ar = tid >> 2, ak = (tid & 3) * 8;   // A staging: 128 rows, 4 thr/row
  const int bc = tid >> 1, bk = (tid & 1) * 16;  // B staging: 256 cols, 2 thr/col

  const int fr = lane & 15;
  const int k0 = (lane >> 4) * 8;

  f32x4 acc[4][4];
  #pragma unroll
  for (int m = 0; m < 4; m++)
    #pragma unroll
    for (int n = 0; n < 4; n++) acc[m][n] = (f32x4){0.f, 0.f, 0.f, 0.f};

  const float* Abase = A + (size_t)row0 * ENC2;
  const short* Bbase = Bt + (size_t)col0 * ENC2;

  float4 aR0, aR1;
  short8 bR0, bR1;

  // prologue: stage kt=0
  aR0 = *(const float4*)(Abase + (size_t)ar * ENC2 + ak);
  aR1 = *(const float4*)(Abase + (size_t)ar * ENC2 + ak + 4);
  bR0 = *(const short8*)(Bbase + (size_t)bc * ENC2 + bk);
  bR1 = *(const short8*)(Bbase + (size_t)bc * ENC2 + bk + 8);
  {
    union { short8 s; unsigned u[4]; } w;
    w.u[0] = pk2(aR0.x, aR0.y); w.u[1] = pk2(aR0.z, aR0.w);
    w.u[2] = pk2(aR1.x, aR1.y); w.u[3] = pk2(aR1.z, aR1.w);
    *(short8*)(&As[0][ar * LDK + ak]) = w.s;
    *(short8*)(&Bs[0][bc * LDK + bk]) = bR0;
    *(short8*)(&Bs[0][bc * LDK + bk + 8]) = bR1;
  }
  __syncthreads();

  const int NT = ENC2 / BK;  // 32
  for (int kt = 0; kt < NT; kt++) {
    const int cur = kt & 1;
    const bool more = (kt + 1 < NT);
    if (more) {
      const float* Ab = Abase + (kt + 1) * BK;
      aR0 = *(const float4*)(Ab + (size_t)ar * ENC2 + ak);
      aR1 = *(const float4*)(Ab + (size_t)ar * ENC2 + ak + 4);
      const short* Bb = Bbase + (kt + 1) * BK;
      bR0 = *(const short8*)(Bb + (size_t)bc * ENC2 + bk);
      bR1 = *(const short8*)(Bb + (size_t)bc * ENC2 + bk + 8);
    }
    short8 af[4], bfr[4];
    #pragma unroll
    for (int m = 0; m < 4; m++)
      af[m] = *(const short8*)(&As[cur][(wm*64 + m*16 + fr) * LDK + k0]);
    #pragma unroll
    for (int n = 0; n < 4; n++)
      bfr[n] = *(const short8*)(&Bs[cur][(wn*64 + n*16 + fr) * LDK + k0]);
    #pragma unroll
    for (int m = 0; m < 4; m++)
      #pragma unroll
      for (int n = 0; n < 4; n++)
        acc[m][n] = __builtin_amdgcn_mfma_f32_16x16x32_bf16(af[m], bfr[n], acc[m][n], 0, 0, 0);
    if (more) {
      union { short8 s; unsigned u[4]; } w;
      w.u[0] = pk2(aR0.x, aR0.y); w.u[1] = pk2(aR0.z, aR0.w);
      w.u[2] = pk2(aR1.x, aR1.y); w.u[3] = pk2(aR1.z, aR1.w);
      *(short8*)(&As[cur ^ 1][ar * LDK + ak]) = w.s;
      *(short8*)(&Bs[cur ^ 1][bc * LDK + bk]) = bR0;
      *(short8*)(&Bs[cur ^ 1][bc * LDK + bk + 8]) = bR1;
    }
    __syncthreads();
  }

  // epilogue: tanh + v-dot; lane-reduce over cols, cross-wn reduce via LDS
  float vv[4], wsb[4];
  #pragma unroll
  for (int n = 0; n < 4; n++) {
    const int gc = col0 + wn*64 + n*16 + fr;
    vv[n]  = vw[gc];
    wsb[n] = Wsb[(size_t)bidx * ATT + gc];
  }
  const int rg = lane >> 4;
  #pragma unroll
  for (int m = 0; m < 4; m++) {
    float part[4] = {0.f, 0.f, 0.f, 0.f};
    #pragma unroll
    for (int n = 0; n < 4; n++) {
      #pragma unroll
      for (int r = 0; r < 4; r++)
        part[r] += vv[n] * fast_tanh(acc[m][n][r] + wsb[n]);
    }
    #pragma unroll
    for (int r = 0; r < 4; r++) {
      float p = part[r];
      p += __shfl_xor(p, 1);
      p += __shfl_xor(p, 2);
      p += __shfl_xor(p, 4);
      p += __shfl_xor(p, 8);
      if (fr == 0) eps[wn][wm*64 + m*16 + rg*4 + r] = p;
    }
  }
  __syncthreads();
  if (tid < BM) {
    float s = eps[0][tid] + eps[1][tid] + eps[2][tid] + eps[3][tid];
    // agent-scope atomic store: coherent across XCDs (bypasses L1/L2 staleness)
    __hip_atomic_store(&epart[(size_t)nt * MTOT + row0 + tid], s,
                       __ATOMIC_RELAXED, __HIP_MEMORY_SCOPE_AGENT);
  }

  // ---- fused softmax: 32nd finishing block of each batch does the row softmax ----
  __threadfence();                 // order this thread's stores device-wide
  __syncthreads();
  if (tid == 0) {
    unsigned old = __hip_atomic_fetch_add(&cnt[bidx], 1u,
                                          __ATOMIC_ACQ_REL, __HIP_MEMORY_SCOPE_AGENT);
    sflag = (old == 31u);
  }
  __syncthreads();
  if (!sflag) return;

  const float* e0 = epart + (size_t)bidx * SEQ;
  const float* e1 = epart + (size_t)MTOT + (size_t)bidx * SEQ;
  float vals[4];
  float mx = -1e30f;
  #pragma unroll
  for (int i = 0; i < 4; i++) {
    float a0 = __hip_atomic_load(&e0[tid + i*512], __ATOMIC_RELAXED, __HIP_MEMORY_SCOPE_AGENT);
    float a1 = __hip_atomic_load(&e1[tid + i*512], __ATOMIC_RELAXED, __HIP_MEMORY_SCOPE_AGENT);
    vals[i] = a0 + a1;
    mx = fmaxf(mx, vals[i]);
  }
  #pragma unroll
  for (int off = 1; off < 64; off <<= 1) mx = fmaxf(mx, __shfl_xor(mx, off));
  if ((tid & 63) == 0) redm[tid >> 6] = mx;
  __syncthreads();
  mx = redm[0];
  #pragma unroll
  for (int i = 1; i < 8; i++) mx = fmaxf(mx, redm[i]);
  float sum = 0.f;
  #pragma unroll
  for (int i = 0; i < 4; i++) { vals[i] = expf(vals[i] - mx); sum += vals[i]; }
  #pragma unroll
  for (int off = 1; off < 64; off <<= 1) sum += __shfl_xor(sum, off);
  if ((tid & 63) == 0) reds[tid >> 6] = sum;
  __syncthreads();
  float tot = 0.f;
  #pragma unroll
  for (int i = 0; i < 8; i++) tot += reds[i];
  const float inv = 1.f / tot;
  #pragma unroll
  for (int i = 0; i < 4; i++) out[(size_t)bidx * SEQ + tid + i*512] = vals[i] * inv;
}

extern "C" void kernel_launch(void* const* d_in, const int* in_sizes, int n_in,
                              void* d_out, int out_size, void* d_ws, size_t ws_size,
                              hipStream_t stream) {
  const float* dh  = (const float*)d_in[0];
  const float* enc = (const float*)d_in[1];
  const float* W_w = (const float*)d_in[2];
  const float* W_b = (const float*)d_in[3];
  const float* U_w = (const float*)d_in[4];
  const float* U_b = (const float*)d_in[5];
  const float* v_w = (const float*)d_in[6];
  float* out = (float*)d_out;

  char* ws = (char*)d_ws;
  float*    epart = (float*)ws;                          // 512 KB
  float*    Wsb   = (float*)(ws + 512 * 1024);           // 64 KB
  short*    U_wT  = (short*)(ws + 576 * 1024);           // 1 MB
  unsigned* cnt   = (unsigned*)(ws + 576 * 1024 + 1024 * 1024);  // 128 B

  hipMemsetAsync(cnt, 0, NBATCH * sizeof(unsigned), stream);
  prep_kernel<<<256, 512, 0, stream>>>(U_w, U_wT, dh, W_w, W_b, U_b, Wsb);
  energy_kernel<<<1024, 512, 0, stream>>>(enc, U_wT, Wsb, v_w, epart, cnt, out);
}

// Round 11
// 138.970 us; speedup vs baseline: 2.5316x; 2.5316x over previous
//
#include <hip/hip_runtime.h>
#include <hip/hip_bf16.h>
#include <math.h>

#define ENC2 1024
#define DECD 1024
#define ATT 512
#define NBATCH 32
#define SEQ 2048
#define MTOT (NBATCH*SEQ)

#define BM 128
#define BN2 256
#define BK 32
#define LDK 40   // padded LDS row stride (80 B -> only 2-way bank alias, free per m136)

typedef __attribute__((ext_vector_type(8))) short short8;
typedef __attribute__((ext_vector_type(4))) short short4v;
typedef __attribute__((ext_vector_type(4))) float f32x4;

static __device__ __forceinline__ unsigned pk2(float a, float b) {
  __hip_bfloat162 h = __float22bfloat162_rn(float2{a, b});  // v_cvt_pk_bf16_f32 (RNE)
  union { __hip_bfloat162 h; unsigned u; } c; c.h = h;
  return c.u;
}

static __device__ __forceinline__ float fast_tanh(float x) {
  float ax = fabsf(x);
  float e = __expf(2.f * ax);          // overflow -> inf -> t -> 1 (correct)
  float t = 1.f - 2.f / (e + 1.f);
  return copysignf(t, x);
}

// ---- fused prep: blocks 0..127 transpose U_w -> U_wT bf16; blocks 128..255
//      compute Wsb[b][a] = dh[b]·W_w[:,a] + W_b[a] + U_b[a] ----
__global__ __launch_bounds__(512) void prep_kernel(
    const float* __restrict__ U_w, short* __restrict__ U_wT,
    const float* __restrict__ dh, const float* __restrict__ W_w,
    const float* __restrict__ W_b, const float* __restrict__ U_b,
    float* __restrict__ Wsb) {
  __shared__ float tile[64][65];      // uwT path
  __shared__ float dsh[DECD];         // ws path
  __shared__ float part[4][128];      // ws path
  const int t = threadIdx.x;

  if (blockIdx.x < 128) {
    // ---- U_w [ENC2][ATT] f32 -> U_wT [ATT][ENC2] bf16, 64x64 tiles ----
    const int kt = blockIdx.x >> 3;      // 16 k-tiles
    const int ct = blockIdx.x & 7;       // 8 c-tiles
    const int k0 = kt * 64, c0 = ct * 64;
    const int r = t >> 3, cc = (t & 7) * 8;
    float4 v0 = *(const float4*)(U_w + (size_t)(k0 + r) * ATT + c0 + cc);
    float4 v1 = *(const float4*)(U_w + (size_t)(k0 + r) * ATT + c0 + cc + 4);
    tile[r][cc+0] = v0.x; tile[r][cc+1] = v0.y; tile[r][cc+2] = v0.z; tile[r][cc+3] = v0.w;
    tile[r][cc+4] = v1.x; tile[r][cc+5] = v1.y; tile[r][cc+6] = v1.z; tile[r][cc+7] = v1.w;
    __syncthreads();
    const int c = t >> 3, kk = (t & 7) * 8;
    union { short8 s; unsigned u[4]; } o;
    o.u[0] = pk2(tile[kk+0][c], tile[kk+1][c]);
    o.u[1] = pk2(tile[kk+2][c], tile[kk+3][c]);
    o.u[2] = pk2(tile[kk+4][c], tile[kk+5][c]);
    o.u[3] = pk2(tile[kk+6][c], tile[kk+7][c]);
    *(short8*)(U_wT + (size_t)(c0 + c) * ENC2 + k0 + kk) = o.s;
  } else {
    // ---- Wsb, K-split x4, 128-col slices ----
    const int bid = blockIdx.x - 128;
    const int b  = bid >> 2;
    const int a0 = (bid & 3) * 128;
    for (int i = t; i < DECD; i += 512) dsh[i] = dh[(size_t)b * DECD + i];
    __syncthreads();
    const int ks = t >> 7;
    const int a  = t & 127;
    const float* wp = W_w + (size_t)(ks * 256) * ATT + a0 + a;
    float s0 = 0.f, s1 = 0.f, s2 = 0.f, s3 = 0.f;
    #pragma unroll 4
    for (int kk = 0; kk < 256; kk += 4) {
      s0 = fmaf(dsh[ks*256 + kk + 0], wp[(size_t)(kk + 0) * ATT], s0);
      s1 = fmaf(dsh[ks*256 + kk + 1], wp[(size_t)(kk + 1) * ATT], s1);
      s2 = fmaf(dsh[ks*256 + kk + 2], wp[(size_t)(kk + 2) * ATT], s2);
      s3 = fmaf(dsh[ks*256 + kk + 3], wp[(size_t)(kk + 3) * ATT], s3);
    }
    part[ks][a] = (s0 + s1) + (s2 + s3);
    __syncthreads();
    if (t < 128) {
      float v = part[0][t] + part[1][t] + part[2][t] + part[3][t];
      Wsb[(size_t)b * ATT + a0 + t] = v + W_b[a0 + t] + U_b[a0 + t];
    }
  }
}

// ---- main: epart[nt][row] = sum_{a in nt-half} v[a]*tanh(enc[row]·U[:,a] + Wsb[b][a])
//      (R2/R7 proven loop: best measured variant) ----
__global__ __launch_bounds__(512) void energy_kernel(
    const float* __restrict__ A,      // encoder [MTOT][ENC2] f32
    const short* __restrict__ Bt,     // U_wT [ATT][ENC2] bf16
    const float* __restrict__ Wsb,    // [NBATCH][ATT]
    const float* __restrict__ vw,     // [ATT]
    float* __restrict__ epart)        // [2][MTOT]
{
  __shared__ __align__(16) short As[2][BM * LDK];
  __shared__ __align__(16) short Bs[2][BN2 * LDK];
  __shared__ float eps[4][BM];        // per-wn-wave partial energies

  const int tid = threadIdx.x;
  const int bid = blockIdx.x;
  // XCD-pairing swizzle: bids 16g+j and 16g+j+8 share mt (same A rows) and
  // have equal bid%8 -> same XCD -> A fetched once per pair from HBM.
  const int mt = (bid >> 4) * 8 + (bid & 7);   // 0..511
  const int nt = (bid >> 3) & 1;               // pair member
  const int row0 = mt * BM;
  const int col0 = nt * BN2;
  const int bidx = row0 / SEQ;

  const int lane = tid & 63;
  const int wid  = tid >> 6;
  const int wm   = wid >> 2;    // 0..1
  const int wn   = wid & 3;     // 0..3

  const int ar = tid >> 2, ak = (tid & 3) * 8;   // A staging: 128 rows, 4 thr/row
  const int bc = tid >> 1, bk = (tid & 1) * 16;  // B staging: 256 cols, 2 thr/col

  const int fr = lane & 15;
  const int k0 = (lane >> 4) * 8;

  f32x4 acc[4][4];
  #pragma unroll
  for (int m = 0; m < 4; m++)
    #pragma unroll
    for (int n = 0; n < 4; n++) acc[m][n] = (f32x4){0.f, 0.f, 0.f, 0.f};

  const float* Abase = A + (size_t)row0 * ENC2;
  const short* Bbase = Bt + (size_t)col0 * ENC2;

  float4 aR0, aR1;
  short8 bR0, bR1;

  // prologue: stage kt=0
  aR0 = *(const float4*)(Abase + (size_t)ar * ENC2 + ak);
  aR1 = *(const float4*)(Abase + (size_t)ar * ENC2 + ak + 4);
  bR0 = *(const short8*)(Bbase + (size_t)bc * ENC2 + bk);
  bR1 = *(const short8*)(Bbase + (size_t)bc * ENC2 + bk + 8);
  {
    union { short8 s; unsigned u[4]; } w;
    w.u[0] = pk2(aR0.x, aR0.y); w.u[1] = pk2(aR0.z, aR0.w);
    w.u[2] = pk2(aR1.x, aR1.y); w.u[3] = pk2(aR1.z, aR1.w);
    *(short8*)(&As[0][ar * LDK + ak]) = w.s;
    *(short8*)(&Bs[0][bc * LDK + bk]) = bR0;
    *(short8*)(&Bs[0][bc * LDK + bk + 8]) = bR1;
  }
  __syncthreads();

  const int NT = ENC2 / BK;  // 32
  for (int kt = 0; kt < NT; kt++) {
    const int cur = kt & 1;
    const bool more = (kt + 1 < NT);
    if (more) {  // issue next-tile global loads; latency hides under ds_read+MFMA
      const float* Ab = Abase + (kt + 1) * BK;
      aR0 = *(const float4*)(Ab + (size_t)ar * ENC2 + ak);
      aR1 = *(const float4*)(Ab + (size_t)ar * ENC2 + ak + 4);
      const short* Bb = Bbase + (kt + 1) * BK;
      bR0 = *(const short8*)(Bb + (size_t)bc * ENC2 + bk);
      bR1 = *(const short8*)(Bb + (size_t)bc * ENC2 + bk + 8);
    }
    short8 af[4], bfr[4];
    #pragma unroll
    for (int m = 0; m < 4; m++)
      af[m] = *(const short8*)(&As[cur][(wm*64 + m*16 + fr) * LDK + k0]);
    #pragma unroll
    for (int n = 0; n < 4; n++)
      bfr[n] = *(const short8*)(&Bs[cur][(wn*64 + n*16 + fr) * LDK + k0]);
    #pragma unroll
    for (int m = 0; m < 4; m++)
      #pragma unroll
      for (int n = 0; n < 4; n++)
        acc[m][n] = __builtin_amdgcn_mfma_f32_16x16x32_bf16(af[m], bfr[n], acc[m][n], 0, 0, 0);
    if (more) {
      union { short8 s; unsigned u[4]; } w;
      w.u[0] = pk2(aR0.x, aR0.y); w.u[1] = pk2(aR0.z, aR0.w);
      w.u[2] = pk2(aR1.x, aR1.y); w.u[3] = pk2(aR1.z, aR1.w);
      *(short8*)(&As[cur ^ 1][ar * LDK + ak]) = w.s;
      *(short8*)(&Bs[cur ^ 1][bc * LDK + bk]) = bR0;
      *(short8*)(&Bs[cur ^ 1][bc * LDK + bk + 8]) = bR1;
    }
    __syncthreads();
  }

  // epilogue: tanh + v-dot; lane-reduce over cols, cross-wn reduce via LDS
  float vv[4], wsb[4];
  #pragma unroll
  for (int n = 0; n < 4; n++) {
    const int gc = col0 + wn*64 + n*16 + fr;
    vv[n]  = vw[gc];
    wsb[n] = Wsb[(size_t)bidx * ATT + gc];
  }
  const int rg = lane >> 4;
  #pragma unroll
  for (int m = 0; m < 4; m++) {
    float part[4] = {0.f, 0.f, 0.f, 0.f};
    #pragma unroll
    for (int n = 0; n < 4; n++) {
      #pragma unroll
      for (int r = 0; r < 4; r++)
        part[r] += vv[n] * fast_tanh(acc[m][n][r] + wsb[n]);
    }
    #pragma unroll
    for (int r = 0; r < 4; r++) {
      float p = part[r];
      p += __shfl_xor(p, 1);
      p += __shfl_xor(p, 2);
      p += __shfl_xor(p, 4);
      p += __shfl_xor(p, 8);
      if (fr == 0) eps[wn][wm*64 + m*16 + rg*4 + r] = p;
    }
  }
  __syncthreads();
  if (tid < BM) {
    float s = eps[0][tid] + eps[1][tid] + eps[2][tid] + eps[3][tid];
    epart[(size_t)nt * MTOT + row0 + tid] = s;
  }
}

// ---- softmax over S=2048 per batch row (sums the 2 partials), 512 thr ----
__global__ __launch_bounds__(512) void softmax_kernel(const float* __restrict__ epart,
                                                      float* __restrict__ out) {
  __shared__ float redmax[8];
  __shared__ float redsum[8];
  const int b = blockIdx.x, t = threadIdx.x;
  const float* e0 = epart + (size_t)b * SEQ;
  const float* e1 = epart + (size_t)MTOT + (size_t)b * SEQ;
  float vals[4];
  float mx = -1e30f;
  #pragma unroll
  for (int i = 0; i < 4; i++) {
    vals[i] = e0[t + i*512] + e1[t + i*512];
    mx = fmaxf(mx, vals[i]);
  }
  #pragma unroll
  for (int off = 1; off < 64; off <<= 1) mx = fmaxf(mx, __shfl_xor(mx, off));
  if ((t & 63) == 0) redmax[t >> 6] = mx;
  __syncthreads();
  mx = redmax[0];
  #pragma unroll
  for (int i = 1; i < 8; i++) mx = fmaxf(mx, redmax[i]);
  float sum = 0.f;
  #pragma unroll
  for (int i = 0; i < 4; i++) { vals[i] = __expf(vals[i] - mx); sum += vals[i]; }
  #pragma unroll
  for (int off = 1; off < 64; off <<= 1) sum += __shfl_xor(sum, off);
  if ((t & 63) == 0) redsum[t >> 6] = sum;
  __syncthreads();
  float tot = 0.f;
  #pragma unroll
  for (int i = 0; i < 8; i++) tot += redsum[i];
  const float inv = 1.f / tot;
  #pragma unroll
  for (int i = 0; i < 4; i++) out[(size_t)b * SEQ + t + i*512] = vals[i] * inv;
}

extern "C" void kernel_launch(void* const* d_in, const int* in_sizes, int n_in,
                              void* d_out, int out_size, void* d_ws, size_t ws_size,
                              hipStream_t stream) {
  const float* dh  = (const float*)d_in[0];
  const float* enc = (const float*)d_in[1];
  const float* W_w = (const float*)d_in[2];
  const float* W_b = (const float*)d_in[3];
  const float* U_w = (const float*)d_in[4];
  const float* U_b = (const float*)d_in[5];
  const float* v_w = (const float*)d_in[6];
  float* out = (float*)d_out;

  char* ws = (char*)d_ws;
  float* epart = (float*)ws;                      // 512 KB (2 x MTOT f32)
  float* Wsb   = (float*)(ws + 512 * 1024);       // 64 KB
  short* U_wT  = (short*)(ws + 576 * 1024);       // 1 MB

  prep_kernel<<<256, 512, 0, stream>>>(U_w, U_wT, dh, W_w, W_b, U_b, Wsb);
  energy_kernel<<<1024, 512, 0, stream>>>(enc, U_wT, Wsb, v_w, epart);
  softmax_kernel<<<NBATCH, 512, 0, stream>>>(epart, out);
}

// Round 12
// 127.617 us; speedup vs baseline: 2.7568x; 1.0890x over previous
//
#include <hip/hip_runtime.h>
#include <hip/hip_bf16.h>
#include <math.h>

#define ENC2 1024
#define DECD 1024
#define ATT 512
#define NBATCH 32
#define SEQ 2048
#define MTOT (NBATCH*SEQ)

#define BM 128
#define BN2 256
#define BK 32
#define LDK 40   // padded LDS row stride (80 B -> only 2-way bank alias, free per m136)

typedef __attribute__((ext_vector_type(8))) short short8;
typedef __attribute__((ext_vector_type(4))) short short4v;
typedef __attribute__((ext_vector_type(4))) float f32x4;

static __device__ __forceinline__ unsigned pk2(float a, float b) {
  __hip_bfloat162 h = __float22bfloat162_rn(float2{a, b});  // v_cvt_pk_bf16_f32 (RNE)
  union { __hip_bfloat162 h; unsigned u; } c; c.h = h;
  return c.u;
}

static __device__ __forceinline__ float fast_tanh(float x) {
  float ax = fabsf(x);
  float e = __expf(2.f * ax);          // overflow -> inf -> t -> 1 (correct)
  float t = 1.f - 2.f / (e + 1.f);
  return copysignf(t, x);
}

// ---- fused prep: blocks 0..127 transpose U_w -> U_wT bf16; blocks 128..255
//      compute Wsb[b][a] = dh[b]·W_w[:,a] + W_b[a] + U_b[a] ----
__global__ __launch_bounds__(512) void prep_kernel(
    const float* __restrict__ U_w, short* __restrict__ U_wT,
    const float* __restrict__ dh, const float* __restrict__ W_w,
    const float* __restrict__ W_b, const float* __restrict__ U_b,
    float* __restrict__ Wsb) {
  __shared__ float tile[64][65];      // uwT path
  __shared__ float dsh[DECD];         // ws path
  __shared__ float part[4][128];      // ws path
  const int t = threadIdx.x;

  if (blockIdx.x < 128) {
    // ---- U_w [ENC2][ATT] f32 -> U_wT [ATT][ENC2] bf16, 64x64 tiles ----
    const int kt = blockIdx.x >> 3;      // 16 k-tiles
    const int ct = blockIdx.x & 7;       // 8 c-tiles
    const int k0 = kt * 64, c0 = ct * 64;
    const int r = t >> 3, cc = (t & 7) * 8;
    float4 v0 = *(const float4*)(U_w + (size_t)(k0 + r) * ATT + c0 + cc);
    float4 v1 = *(const float4*)(U_w + (size_t)(k0 + r) * ATT + c0 + cc + 4);
    tile[r][cc+0] = v0.x; tile[r][cc+1] = v0.y; tile[r][cc+2] = v0.z; tile[r][cc+3] = v0.w;
    tile[r][cc+4] = v1.x; tile[r][cc+5] = v1.y; tile[r][cc+6] = v1.z; tile[r][cc+7] = v1.w;
    __syncthreads();
    const int c = t >> 3, kk = (t & 7) * 8;
    union { short8 s; unsigned u[4]; } o;
    o.u[0] = pk2(tile[kk+0][c], tile[kk+1][c]);
    o.u[1] = pk2(tile[kk+2][c], tile[kk+3][c]);
    o.u[2] = pk2(tile[kk+4][c], tile[kk+5][c]);
    o.u[3] = pk2(tile[kk+6][c], tile[kk+7][c]);
    *(short8*)(U_wT + (size_t)(c0 + c) * ENC2 + k0 + kk) = o.s;
  } else {
    // ---- Wsb, K-split x4, 128-col slices ----
    const int bid = blockIdx.x - 128;
    const int b  = bid >> 2;
    const int a0 = (bid & 3) * 128;
    for (int i = t; i < DECD; i += 512) dsh[i] = dh[(size_t)b * DECD + i];
    __syncthreads();
    const int ks = t >> 7;
    const int a  = t & 127;
    const float* wp = W_w + (size_t)(ks * 256) * ATT + a0 + a;
    float s0 = 0.f, s1 = 0.f, s2 = 0.f, s3 = 0.f;
    #pragma unroll 4
    for (int kk = 0; kk < 256; kk += 4) {
      s0 = fmaf(dsh[ks*256 + kk + 0], wp[(size_t)(kk + 0) * ATT], s0);
      s1 = fmaf(dsh[ks*256 + kk + 1], wp[(size_t)(kk + 1) * ATT], s1);
      s2 = fmaf(dsh[ks*256 + kk + 2], wp[(size_t)(kk + 2) * ATT], s2);
      s3 = fmaf(dsh[ks*256 + kk + 3], wp[(size_t)(kk + 3) * ATT], s3);
    }
    part[ks][a] = (s0 + s1) + (s2 + s3);
    __syncthreads();
    if (t < 128) {
      float v = part[0][t] + part[1][t] + part[2][t] + part[3][t];
      Wsb[(size_t)b * ATT + a0 + t] = v + W_b[a0 + t] + U_b[a0 + t];
    }
  }
}

// ---- main: epart[nt][row] = sum_{a in nt-half} v[a]*tanh(enc[row]·U[:,a] + Wsb[b][a])
//      (R2/R7 proven loop: best measured variant across 7 structures) ----
__global__ __launch_bounds__(512) void energy_kernel(
    const float* __restrict__ A,      // encoder [MTOT][ENC2] f32
    const short* __restrict__ Bt,     // U_wT [ATT][ENC2] bf16
    const float* __restrict__ Wsb,    // [NBATCH][ATT]
    const float* __restrict__ vw,     // [ATT]
    float* __restrict__ epart)        // [2][MTOT]
{
  __shared__ __align__(16) short As[2][BM * LDK];
  __shared__ __align__(16) short Bs[2][BN2 * LDK];
  __shared__ float eps[4][BM];        // per-wn-wave partial energies

  const int tid = threadIdx.x;
  const int bid = blockIdx.x;
  // XCD-pairing swizzle: bids 16g+j and 16g+j+8 share mt (same A rows) and
  // have equal bid%8 -> same XCD -> A fetched once per pair from HBM.
  const int mt = (bid >> 4) * 8 + (bid & 7);   // 0..511
  const int nt = (bid >> 3) & 1;               // pair member
  const int row0 = mt * BM;
  const int col0 = nt * BN2;
  const int bidx = row0 / SEQ;

  const int lane = tid & 63;
  const int wid  = tid >> 6;
  const int wm   = wid >> 2;    // 0..1
  const int wn   = wid & 3;     // 0..3

  const int ar = tid >> 2, ak = (tid & 3) * 8;   // A staging: 128 rows, 4 thr/row
  const int bc = tid >> 1, bk = (tid & 1) * 16;  // B staging: 256 cols, 2 thr/col

  const int fr = lane & 15;
  const int k0 = (lane >> 4) * 8;

  f32x4 acc[4][4];
  #pragma unroll
  for (int m = 0; m < 4; m++)
    #pragma unroll
    for (int n = 0; n < 4; n++) acc[m][n] = (f32x4){0.f, 0.f, 0.f, 0.f};

  const float* Abase = A + (size_t)row0 * ENC2;
  const short* Bbase = Bt + (size_t)col0 * ENC2;

  float4 aR0, aR1;
  short8 bR0, bR1;

  // prologue: stage kt=0
  aR0 = *(const float4*)(Abase + (size_t)ar * ENC2 + ak);
  aR1 = *(const float4*)(Abase + (size_t)ar * ENC2 + ak + 4);
  bR0 = *(const short8*)(Bbase + (size_t)bc * ENC2 + bk);
  bR1 = *(const short8*)(Bbase + (size_t)bc * ENC2 + bk + 8);
  {
    union { short8 s; unsigned u[4]; } w;
    w.u[0] = pk2(aR0.x, aR0.y); w.u[1] = pk2(aR0.z, aR0.w);
    w.u[2] = pk2(aR1.x, aR1.y); w.u[3] = pk2(aR1.z, aR1.w);
    *(short8*)(&As[0][ar * LDK + ak]) = w.s;
    *(short8*)(&Bs[0][bc * LDK + bk]) = bR0;
    *(short8*)(&Bs[0][bc * LDK + bk + 8]) = bR1;
  }
  __syncthreads();

  const int NT = ENC2 / BK;  // 32
  for (int kt = 0; kt < NT; kt++) {
    const int cur = kt & 1;
    const bool more = (kt + 1 < NT);
    if (more) {  // issue next-tile global loads; latency hides under ds_read+MFMA
      const float* Ab = Abase + (kt + 1) * BK;
      aR0 = *(const float4*)(Ab + (size_t)ar * ENC2 + ak);
      aR1 = *(const float4*)(Ab + (size_t)ar * ENC2 + ak + 4);
      const short* Bb = Bbase + (kt + 1) * BK;
      bR0 = *(const short8*)(Bb + (size_t)bc * ENC2 + bk);
      bR1 = *(const short8*)(Bb + (size_t)bc * ENC2 + bk + 8);
    }
    short8 af[4], bfr[4];
    #pragma unroll
    for (int m = 0; m < 4; m++)
      af[m] = *(const short8*)(&As[cur][(wm*64 + m*16 + fr) * LDK + k0]);
    #pragma unroll
    for (int n = 0; n < 4; n++)
      bfr[n] = *(const short8*)(&Bs[cur][(wn*64 + n*16 + fr) * LDK + k0]);
    #pragma unroll
    for (int m = 0; m < 4; m++)
      #pragma unroll
      for (int n = 0; n < 4; n++)
        acc[m][n] = __builtin_amdgcn_mfma_f32_16x16x32_bf16(af[m], bfr[n], acc[m][n], 0, 0, 0);
    if (more) {
      union { short8 s; unsigned u[4]; } w;
      w.u[0] = pk2(aR0.x, aR0.y); w.u[1] = pk2(aR0.z, aR0.w);
      w.u[2] = pk2(aR1.x, aR1.y); w.u[3] = pk2(aR1.z, aR1.w);
      *(short8*)(&As[cur ^ 1][ar * LDK + ak]) = w.s;
      *(short8*)(&Bs[cur ^ 1][bc * LDK + bk]) = bR0;
      *(short8*)(&Bs[cur ^ 1][bc * LDK + bk + 8]) = bR1;
    }
    __syncthreads();
  }

  // epilogue: tanh + v-dot; lane-reduce over cols, cross-wn reduce via LDS
  float vv[4], wsb[4];
  #pragma unroll
  for (int n = 0; n < 4; n++) {
    const int gc = col0 + wn*64 + n*16 + fr;
    vv[n]  = vw[gc];
    wsb[n] = Wsb[(size_t)bidx * ATT + gc];
  }
  const int rg = lane >> 4;
  #pragma unroll
  for (int m = 0; m < 4; m++) {
    float part[4] = {0.f, 0.f, 0.f, 0.f};
    #pragma unroll
    for (int n = 0; n < 4; n++) {
      #pragma unroll
      for (int r = 0; r < 4; r++)
        part[r] += vv[n] * fast_tanh(acc[m][n][r] + wsb[n]);
    }
    #pragma unroll
    for (int r = 0; r < 4; r++) {
      float p = part[r];
      p += __shfl_xor(p, 1);
      p += __shfl_xor(p, 2);
      p += __shfl_xor(p, 4);
      p += __shfl_xor(p, 8);
      if (fr == 0) eps[wn][wm*64 + m*16 + rg*4 + r] = p;
    }
  }
  __syncthreads();
  if (tid < BM) {
    float s = eps[0][tid] + eps[1][tid] + eps[2][tid] + eps[3][tid];
    epart[(size_t)nt * MTOT + row0 + tid] = s;
  }
}

// ---- softmax over S=2048 per batch row (sums the 2 partials), 512 thr ----
__global__ __launch_bounds__(512) void softmax_kernel(const float* __restrict__ epart,
                                                      float* __restrict__ out) {
  __shared__ float redmax[8];
  __shared__ float redsum[8];
  const int b = blockIdx.x, t = threadIdx.x;
  const float* e0 = epart + (size_t)b * SEQ;
  const float* e1 = epart + (size_t)MTOT + (size_t)b * SEQ;
  float vals[4];
  float mx = -1e30f;
  #pragma unroll
  for (int i = 0; i < 4; i++) {
    vals[i] = e0[t + i*512] + e1[t + i*512];
    mx = fmaxf(mx, vals[i]);
  }
  #pragma unroll
  for (int off = 1; off < 64; off <<= 1) mx = fmaxf(mx, __shfl_xor(mx, off));
  if ((t & 63) == 0) redmax[t >> 6] = mx;
  __syncthreads();
  mx = redmax[0];
  #pragma unroll
  for (int i = 1; i < 8; i++) mx = fmaxf(mx, redmax[i]);
  float sum = 0.f;
  #pragma unroll
  for (int i = 0; i < 4; i++) { vals[i] = expf(vals[i] - mx); sum += vals[i]; }
  #pragma unroll
  for (int off = 1; off < 64; off <<= 1) sum += __shfl_xor(sum, off);
  if ((t & 63) == 0) redsum[t >> 6] = sum;
  __syncthreads();
  float tot = 0.f;
  #pragma unroll
  for (int i = 0; i < 8; i++) tot += redsum[i];
  const float inv = 1.f / tot;
  #pragma unroll
  for (int i = 0; i < 4; i++) out[(size_t)b * SEQ + t + i*512] = vals[i] * inv;
}

extern "C" void kernel_launch(void* const* d_in, const int* in_sizes, int n_in,
                              void* d_out, int out_size, void* d_ws, size_t ws_size,
                              hipStream_t stream) {
  const float* dh  = (const float*)d_in[0];
  const float* enc = (const float*)d_in[1];
  const float* W_w = (const float*)d_in[2];
  const float* W_b = (const float*)d_in[3];
  const float* U_w = (const float*)d_in[4];
  const float* U_b = (const float*)d_in[5];
  const float* v_w = (const float*)d_in[6];
  float* out = (float*)d_out;

  char* ws = (char*)d_ws;
  float* epart = (float*)ws;                      // 512 KB (2 x MTOT f32)
  float* Wsb   = (float*)(ws + 512 * 1024);       // 64 KB
  short* U_wT  = (short*)(ws + 576 * 1024);       // 1 MB

  prep_kernel<<<256, 512, 0, stream>>>(U_w, U_wT, dh, W_w, W_b, U_b, Wsb);
  energy_kernel<<<1024, 512, 0, stream>>>(enc, U_wT, Wsb, v_w, epart);
  softmax_kernel<<<NBATCH, 512, 0, stream>>>(epart, out);
}